// Round 12
// baseline (250.816 us; speedup 1.0000x reference)
//
#include <hip/hip_runtime.h>
#include <cstdint>
#include <cstddef>

// RNNT joiner: logits[b,t,u,v] = sum_j tanh(E[b,t,j]+P[b,u,j]) * out_w[v,j] + out_b[v]
// B=4 T=256 U=64 D=512 J=640 V=1024.  M = 65536 rows (b,t,u), N=1024, K=640.
//
// ws layout (Z-path, R8 layouts):
//   E  : bf16 [1024][640]                  @ 0          (1,310,720 B)
//   P  : bf16 [ 256][640]                  @ 1,310,720  (  327,680 B)
//   Wb : bf16 [nt=4][kt=10][half=2][8192]  @ 1,638,400  (1,310,720 B)  pre-swz 128x64 half-tiles
//   Z  : bf16 [mt=256][kt=10][half=2][8192]@ 2,949,120  (83,886,080 B) pre-swz 128x64 half-tiles
// total 86,835,200 B.  ws_size smaller -> fused fallback.

typedef __attribute__((ext_vector_type(8))) __bf16 bf16x8;
typedef __attribute__((ext_vector_type(4))) float f32x4;

// XOR swizzle within a [128][64] bf16 half-tile (row stride 128B).
__device__ __forceinline__ int swz64(int row, int kElem) {
  return (row << 6) + (kElem ^ ((row & 7) << 3));
}

__device__ __forceinline__ float fast_tanh(float x) {
  float e = __builtin_amdgcn_exp2f(x * 2.88539008177793f);  // e^(2x)
  return 1.0f - 2.0f * __builtin_amdgcn_rcpf(e + 1.0f);
}

__device__ __forceinline__ void gload_lds16(const void* g, void* l) {
  __builtin_amdgcn_global_load_lds(
      (const __attribute__((address_space(1))) void*)g,
      (__attribute__((address_space(3))) void*)l, 16, 0, 0);
}

// Barrier that is also a compiler-level memory fence (zero extra HW instrs).
__device__ __forceinline__ void wg_barrier() {
  asm volatile("" ::: "memory");
  __builtin_amdgcn_s_barrier();
  asm volatile("" ::: "memory");
}

// ---------------------------------------------------------------------------
// proj tile: C[mt*128..][nt*128..] = A[128][512] . W[128][512]^T + bias  (bf16 out)
// ---------------------------------------------------------------------------
__device__ void proj_tile(const float* __restrict__ A, const float* __restrict__ W,
                          const float* __restrict__ bias, __bf16* __restrict__ C,
                          int mt, int nt, __bf16* As, __bf16* Bs)
{
  const int tid  = threadIdx.x;
  const int r = tid & 127, half = tid >> 7;
  const int lane = tid & 63, wv = tid >> 6;
  const int wm = wv >> 1, wn = wv & 1;

  const float* arow = A + (size_t)(mt * 128 + r) * 512 + half * 32;
  const float* wrow = W + (size_t)(nt * 128 + r) * 512 + half * 32;

  f32x4 acc[4][4] = {};

  for (int k0 = 0; k0 < 512; k0 += 64) {
#pragma unroll
    for (int s = 0; s < 4; ++s) {
      f32x4 a0 = *(const f32x4*)(arow + k0 + s * 8);
      f32x4 a1 = *(const f32x4*)(arow + k0 + s * 8 + 4);
      f32x4 w0 = *(const f32x4*)(wrow + k0 + s * 8);
      f32x4 w1 = *(const f32x4*)(wrow + k0 + s * 8 + 4);
      bf16x8 za, zw;
#pragma unroll
      for (int j = 0; j < 4; ++j) {
        za[j] = (__bf16)a0[j]; za[4 + j] = (__bf16)a1[j];
        zw[j] = (__bf16)w0[j]; zw[4 + j] = (__bf16)w1[j];
      }
      const int kk = half * 32 + s * 8;
      *(bf16x8*)&As[swz64(r, kk)] = za;
      *(bf16x8*)&Bs[swz64(r, kk)] = zw;
    }
    __syncthreads();
#pragma unroll
    for (int kk = 0; kk < 2; ++kk) {
      bf16x8 af[4], bfr[4];
#pragma unroll
      for (int i = 0; i < 4; ++i) {
        af[i]  = *(const bf16x8*)&As[swz64(wm * 64 + i * 16 + (lane & 15), kk * 32 + (lane >> 4) * 8)];
        bfr[i] = *(const bf16x8*)&Bs[swz64(wn * 64 + i * 16 + (lane & 15), kk * 32 + (lane >> 4) * 8)];
      }
#pragma unroll
      for (int mi = 0; mi < 4; ++mi)
#pragma unroll
        for (int ni = 0; ni < 4; ++ni)
          acc[mi][ni] = __builtin_amdgcn_mfma_f32_16x16x32_bf16(af[mi], bfr[ni], acc[mi][ni], 0, 0, 0);
    }
    __syncthreads();
  }

  const int rowbase = mt * 128 + wm * 64;
  const int colbase = nt * 128 + wn * 64;
#pragma unroll
  for (int ni = 0; ni < 4; ++ni) {
    const int col = colbase + ni * 16 + (lane & 15);
    const float bb = bias[col];
#pragma unroll
    for (int mi = 0; mi < 4; ++mi) {
      const int row = rowbase + mi * 16 + (lane >> 4) * 4;
#pragma unroll
      for (int rg = 0; rg < 4; ++rg)
        C[(size_t)(row + rg) * 640 + col] = (__bf16)(acc[mi][ni][rg] + bb);
    }
  }
}

// ---------------------------------------------------------------------------
// prep: blocks 0..39 enc-proj, 40..49 pred-proj, 50..369 out_w conversion.
// zpath=1: Wb [nt(4)][kt(10)][half(2)][128x64 swz64].
// zpath=0: Wb [nb(8)][kt(10)][128x64 swz64]  (fallback layout).
// ---------------------------------------------------------------------------
__global__ __launch_bounds__(256) void prep_kernel(
    const float* __restrict__ enc,  const float* __restrict__ enc_w,  const float* __restrict__ enc_b,
    const float* __restrict__ pred, const float* __restrict__ pred_w, const float* __restrict__ pred_b,
    const float* __restrict__ out_w,
    __bf16* __restrict__ E, __bf16* __restrict__ P, __bf16* __restrict__ Wb, int zpath)
{
  __shared__ __align__(16) __bf16 As[128 * 64];
  __shared__ __align__(16) __bf16 Bs[128 * 64];
  const int bid = blockIdx.x;
  if (bid < 40) {
    proj_tile(enc, enc_w, enc_b, E, bid / 5, bid % 5, As, Bs);
  } else if (bid < 50) {
    proj_tile(pred, pred_w, pred_b, P, (bid - 40) / 5, (bid - 40) % 5, As, Bs);
  } else {
    const int gid = (bid - 50) * 256 + threadIdx.x;  // 81920 total (1024*80)
    const int v  = gid / 80;
    const int j8 = gid % 80;
    f32x4 w0 = *(const f32x4*)(out_w + (size_t)v * 640 + j8 * 8);
    f32x4 w1 = *(const f32x4*)(out_w + (size_t)v * 640 + j8 * 8 + 4);
    bf16x8 z;
#pragma unroll
    for (int j = 0; j < 4; ++j) { z[j] = (__bf16)w0[j]; z[4 + j] = (__bf16)w1[j]; }
    if (zpath) {
      const int nt = v >> 8, vv = v & 255;
      const int half = vv >> 7, rr = vv & 127;
      const int kt = j8 >> 3, kk = (j8 & 7) * 8;
      *(bf16x8*)(Wb + (((size_t)(nt * 10 + kt) * 2 + half) << 13) + swz64(rr, kk)) = z;
    } else {
      const int nb = v >> 7, rr = v & 127;
      const int kb = j8 >> 3, kk = (j8 & 7) * 8;
      *(bf16x8*)(Wb + ((size_t)(nb * 10 + kb) << 13) + swz64(rr, kk)) = z;
    }
  }
}

// ---------------------------------------------------------------------------
// zprod: Z[mt][kt][half][8192] = tanh(E+P), pre-swizzled half-tiles, LINEAR
// stores (swizzle inverted at source index).  grid = 2560 (mt*10+kt), 256 thr.
// ---------------------------------------------------------------------------
__global__ __launch_bounds__(256) void zprod_kernel(
    const __bf16* __restrict__ E, const __bf16* __restrict__ P,
    __bf16* __restrict__ Z)
{
  const int bid = blockIdx.x;
  const int mt = bid / 10, kt = bid % 10;
  __bf16* zdst = Z + ((size_t)bid << 14);      // 16384 elems per (mt,kt)

#pragma unroll
  for (int c = 0; c < 8; ++c) {
    const int o = c * 2048 + threadIdx.x * 8;  // linear offset in 16K-elem block
    const int half = o >> 13, oo = o & 8191;
    const int rr = oo >> 6;
    const int r = half * 128 + rr;             // tile row 0..255
    const int k = kt * 64 + ((oo & 63) ^ ((rr & 7) << 3));
    const int grow = mt * 256 + r;             // global M-row
    const __bf16* ep = E + (size_t)(grow >> 6) * 640 + k;
    const __bf16* pp = P + (size_t)(((grow >> 14) << 6) | (grow & 63)) * 640 + k;
    bf16x8 e8 = *(const bf16x8*)ep;
    bf16x8 p8 = *(const bf16x8*)pp;
    bf16x8 z;
#pragma unroll
    for (int j = 0; j < 8; ++j)
      z[j] = (__bf16)fast_tanh((float)e8[j] + (float)p8[j]);
    *(bf16x8*)&zdst[o] = z;
  }
}

// ---------------------------------------------------------------------------
// main (Z-path): M-persistent 8-phase GEMM.  Grid 256 = 1 block/CU; each
// block owns nt (256 N-cols) and FOUR consecutive 256-row M-tiles.  The
// half-tile stage stream [A0,B0,B1,A1] runs continuously across all 40
// logical tiles (t = i*10+kt; 10 even -> dbuf parity kt&1 seamless);
// vmcnt(6) counted throughout, drained once at t=39.  One prologue total;
// epilogue stores of tiles 0..2 drain under the next tile's compute.
// 512 thr = 8 waves (2M x 4N), wave-tile 128x64, interleaved frags
// (P0={A0,B0} P1={B1} P2={A1} P3={regs}).  LDS 128 KB.  Bias pre-loaded
// into acc init.  XCD-chunked bid: the 4 readers of each Z-strip share L2.
// ---------------------------------------------------------------------------
__global__ __launch_bounds__(512, 2) void joiner_8pm(
    const __bf16* __restrict__ Z, const __bf16* __restrict__ Wb,
    const float* __restrict__ outb, float* __restrict__ out)
{
  __shared__ __align__(16) __bf16 As[2][2][8192];   // [dbuf][half][128x64]
  __shared__ __align__(16) __bf16 Bs[2][2][8192];
  const int wg = blockIdx.x;
  const int bid = (wg & 7) * 32 + (wg >> 3);        // XCD-contiguous chunks (256%8==0)
  const int nt = bid & 3, mtg = bid >> 2;           // mtg 0..63
  const int tid = threadIdx.x;
  const int lane = tid & 63, wv = tid >> 6;
  const int wm = wv >> 2, wn = wv & 3;              // 2 x 4 wave grid

  const int rb  = wm * 16 + (lane & 15);            // A row base within 32-row group
  const int cb  = wn * 16 + (lane & 15);            // B col base within 64-col group
  const int kb8 = (lane >> 4) * 8;

  const size_t ZSTRIDE = (size_t)20 << 13;          // 163840 elems per 256-row strip
  const __bf16* zc = Z + (size_t)(mtg * 4) * ZSTRIDE;
  const __bf16* wsrc = Wb + ((size_t)(nt * 20) << 13);

  const int colbase = (nt << 8) + wn * 16 + (lane & 15);
  float bv[4];
#pragma unroll
  for (int g = 0; g < 4; ++g) bv[g] = outb[colbase + g * 64];

  f32x4 acc[8][4];
#pragma unroll
  for (int f = 0; f < 8; ++f)
#pragma unroll
    for (int g = 0; g < 4; ++g)
      acc[f][g] = (f32x4){bv[g], bv[g], bv[g], bv[g]};

  auto stA = [&](const __bf16* zp, int kt, int half) {
    __bf16* dst = &As[kt & 1][half][wv * 512];
    const __bf16* src = zp + (((size_t)kt * 2 + half) << 13) + wv * 512 + lane * 8;
    gload_lds16(src, dst);
    gload_lds16(src + 4096, dst + 4096);
  };
  auto stB = [&](int kt, int half) {
    __bf16* dst = &Bs[kt & 1][half][wv * 512];
    const __bf16* src = wsrc + (((size_t)kt * 2 + half) << 13) + wv * 512 + lane * 8;
    gload_lds16(src, dst);
    gload_lds16(src + 4096, dst + 4096);
  };

  // ---- prologue (once): stage stream s=0..6 = T0{A0,B0,B1,A1} T1{A0,B0,B1} ----
  stA(zc, 0, 0); stB(0, 0); stB(0, 1); stA(zc, 0, 1);
  stA(zc, 1, 0); stB(1, 0); stB(1, 1);
  asm volatile("s_waitcnt vmcnt(6)" ::: "memory");
  wg_barrier();

  for (int i = 0; i < 4; ++i, zc += ZSTRIDE) {
    const __bf16* zn = zc + ZSTRIDE;   // next strip (guarded: never used at i==3)
    const int last = (i == 3);

#pragma unroll
    for (int k = 0; k < 10; ++k) {
      const int d = k & 1;
      const __bf16* A0 = &As[d][0][0];
      const __bf16* A1 = &As[d][1][0];
      const __bf16* B0 = &Bs[d][0][0];
      const __bf16* B1 = &Bs[d][1][0];
      bf16x8 afl[4][2], afh[4][2], bl[2][2], bh[2][2];

      // ===== P0: reads A0,B0; stage A1(t+1); vmcnt; MFMA f0-3 x g0-1 =====
#pragma unroll
      for (int f = 0; f < 4; ++f)
#pragma unroll
        for (int kk = 0; kk < 2; ++kk)
          afl[f][kk] = *(const bf16x8*)&A0[swz64(f * 32 + rb, kk * 32 + kb8)];
#pragma unroll
      for (int g = 0; g < 2; ++g)
#pragma unroll
        for (int kk = 0; kk < 2; ++kk)
          bl[g][kk] = *(const bf16x8*)&B0[swz64(g * 64 + cb, kk * 32 + kb8)];
      if (k < 9)      stA(zc, k + 1, 1);
      else if (!last) stA(zn, 0, 1);
      if (k == 9 && last) asm volatile("s_waitcnt vmcnt(0)" ::: "memory");
      else                asm volatile("s_waitcnt vmcnt(6)" ::: "memory");
      wg_barrier();
      asm volatile("s_waitcnt lgkmcnt(0)" ::: "memory");
      __builtin_amdgcn_sched_barrier(0);
      __builtin_amdgcn_s_setprio(1);
#pragma unroll
      for (int kk = 0; kk < 2; ++kk)
#pragma unroll
        for (int f = 0; f < 4; ++f)
#pragma unroll
          for (int g = 0; g < 2; ++g)
            acc[f][g] = __builtin_amdgcn_mfma_f32_16x16x32_bf16(afl[f][kk], bl[g][kk], acc[f][g], 0, 0, 0);
      __builtin_amdgcn_s_setprio(0);
      wg_barrier();

      // ===== P1: reads B1; stage A0(t+2); MFMA f0-3 x g2-3 =====
#pragma unroll
      for (int g = 0; g < 2; ++g)
#pragma unroll
        for (int kk = 0; kk < 2; ++kk)
          bh[g][kk] = *(const bf16x8*)&B1[swz64(g * 64 + cb, kk * 32 + kb8)];
      if (k < 8)      stA(zc, k + 2, 0);
      else if (!last) stA(zn, k - 8, 0);
      wg_barrier();
      asm volatile("s_waitcnt lgkmcnt(0)" ::: "memory");
      __builtin_amdgcn_sched_barrier(0);
      __builtin_amdgcn_s_setprio(1);
#pragma unroll
      for (int kk = 0; kk < 2; ++kk)
#pragma unroll
        for (int f = 0; f < 4; ++f)
#pragma unroll
          for (int g = 0; g < 2; ++g)
            acc[f][2 + g] = __builtin_amdgcn_mfma_f32_16x16x32_bf16(afl[f][kk], bh[g][kk], acc[f][2 + g], 0, 0, 0);
      __builtin_amdgcn_s_setprio(0);
      wg_barrier();

      // ===== P2: reads A1; stage B0(t+2); MFMA f4-7 x g2-3 =====
#pragma unroll
      for (int f = 0; f < 4; ++f)
#pragma unroll
        for (int kk = 0; kk < 2; ++kk)
          afh[f][kk] = *(const bf16x8*)&A1[swz64(f * 32 + rb, kk * 32 + kb8)];
      if (k < 8)      stB(k + 2, 0);
      else if (!last) stB(k - 8, 0);
      wg_barrier();
      asm volatile("s_waitcnt lgkmcnt(0)" ::: "memory");
      __builtin_amdgcn_sched_barrier(0);
      __builtin_amdgcn_s_setprio(1);
#pragma unroll
      for (int kk = 0; kk < 2; ++kk)
#pragma unroll
        for (int f = 0; f < 4; ++f)
#pragma unroll
          for (int g = 0; g < 2; ++g)
            acc[4 + f][2 + g] = __builtin_amdgcn_mfma_f32_16x16x32_bf16(afh[f][kk], bh[g][kk], acc[4 + f][2 + g], 0, 0, 0);
      __builtin_amdgcn_s_setprio(0);
      wg_barrier();

      // ===== P3: register-only; stage B1(t+2); MFMA f4-7 x g0-1 =====
      if (k < 8)      stB(k + 2, 1);
      else if (!last) stB(k - 8, 1);
      __builtin_amdgcn_s_setprio(1);
#pragma unroll
      for (int kk = 0; kk < 2; ++kk)
#pragma unroll
        for (int f = 0; f < 4; ++f)
#pragma unroll
          for (int g = 0; g < 2; ++g)
            acc[4 + f][g] = __builtin_amdgcn_mfma_f32_16x16x32_bf16(afh[f][kk], bl[g][kk], acc[4 + f][g], 0, 0, 0);
      __builtin_amdgcn_s_setprio(0);
      wg_barrier();   // tile boundary
    }

    // ---- per-tile epilogue: pure stores (bias already in acc) ----
    const int rowbase = ((mtg * 4 + i) << 8) + wm * 16 + (lane >> 4) * 4;
#pragma unroll
    for (int g = 0; g < 4; ++g) {
      const int col = colbase + g * 64;
#pragma unroll
      for (int f = 0; f < 8; ++f) {
        const int row = rowbase + f * 32;
#pragma unroll
        for (int rg = 0; rg < 4; ++rg)
          out[(size_t)(row + rg) * 1024 + col] = acc[f][g][rg];
      }
    }
    if (i < 3) {
#pragma unroll
      for (int f = 0; f < 8; ++f)
#pragma unroll
        for (int g = 0; g < 4; ++g)
          acc[f][g] = (f32x4){bv[g], bv[g], bv[g], bv[g]};
    }
  }
}

// ---------------------------------------------------------------------------
// Fallback (small ws): R5 fused kernel, Wb in [8][10][128x64 swz64] layout.
// ---------------------------------------------------------------------------
__global__ __launch_bounds__(512, 4) void joiner_fused(
    const __bf16* __restrict__ E, const __bf16* __restrict__ P,
    const __bf16* __restrict__ Wb, const float* __restrict__ outb,
    float* __restrict__ out)
{
  __shared__ __align__(16) __bf16 As[8192];
  __shared__ __align__(16) __bf16 Bs[2][16384];
  const int tid = threadIdx.x;
  const int nt = blockIdx.x & 3;
  const int mt = blockIdx.x >> 2;
  const int row0 = mt << 7;
  const int b  = row0 >> 14;
  const int t0 = (row0 >> 6) & 255;
  const int ar = tid & 127, h = tid >> 7;
  const int lane = tid & 63, wv = tid >> 6;
  const int wm = wv >> 2, wn = wv & 3;

  const __bf16* ep = E + (size_t)((b << 8) + t0 + (ar >> 6)) * 640 + h * 16;
  const __bf16* pp = P + (size_t)((b << 6) + (ar & 63)) * 640 + h * 16;

  f32x4 acc[4][4] = {};
  bf16x8 eA[2], pA[2];

  auto stageB2 = [&](int kt, __bf16* dst) {
#pragma unroll
    for (int c = 0; c < 4; ++c) {
      const int blk = nt * 2 + (c >> 1);
      const int inoff = (c & 1) * 4096 + wv * 512;
      gload_lds16(Wb + ((size_t)(blk * 10 + kt) << 13) + inoff + lane * 8,
                  dst + (c >> 1) * 8192 + inoff);
    }
  };
  auto loadEP = [&](int k0) {
#pragma unroll
    for (int c = 0; c < 2; ++c) {
      eA[c] = *(const bf16x8*)(ep + k0 + c * 8);
      pA[c] = *(const bf16x8*)(pp + k0 + c * 8);
    }
  };
  auto writeA = [&]() {
#pragma unroll
    for (int c = 0; c < 2; ++c) {
      bf16x8 z;
#pragma unroll
      for (int j = 0; j < 8; ++j)
        z[j] = (__bf16)fast_tanh((float)eA[c][j] + (float)pA[c][j]);
      *(bf16x8*)&As[swz64(ar, h * 16 + c * 8)] = z;
    }
  };
  auto compute = [&](const __bf16* Bsc) {
#pragma unroll
    for (int kk = 0; kk < 2; ++kk) {
      bf16x8 af[4], bfr[4];
#pragma unroll
      for (int i = 0; i < 4; ++i) {
        af[i]  = *(const bf16x8*)&As[swz64(wm * 64 + i * 16 + (lane & 15), kk * 32 + (lane >> 4) * 8)];
        bfr[i] = *(const bf16x8*)&Bsc[swz64(wn * 64 + i * 16 + (lane & 15), kk * 32 + (lane >> 4) * 8)];
      }
      asm volatile("s_waitcnt lgkmcnt(0)" ::: "memory");
      __builtin_amdgcn_sched_barrier(0);
      __builtin_amdgcn_s_setprio(1);
#pragma unroll
      for (int mi = 0; mi < 4; ++mi)
#pragma unroll
        for (int ni = 0; ni < 4; ++ni)
          acc[mi][ni] = __builtin_amdgcn_mfma_f32_16x16x32_bf16(af[mi], bfr[ni], acc[mi][ni], 0, 0, 0);
      __builtin_amdgcn_s_setprio(0);
    }
  };

  stageB2(0, Bs[0]);
  loadEP(0);
  writeA();
  asm volatile("s_waitcnt vmcnt(0) lgkmcnt(0)" ::: "memory");
  wg_barrier();

  for (int kt = 0; kt < 9; ++kt) {
    const int cur = kt & 1;
    stageB2(kt + 1, Bs[cur ^ 1]);
    loadEP((kt + 1) << 6);
    compute(Bs[cur]);
    wg_barrier();
    __builtin_amdgcn_sched_barrier(0);
    writeA();
    asm volatile("s_waitcnt lgkmcnt(0)" ::: "memory");
    wg_barrier();
  }
  compute(Bs[1]);

  const int rowbase = row0 + wm * 64;
  const int colbase = (nt << 8) + wn * 64;
#pragma unroll
  for (int ni = 0; ni < 4; ++ni) {
    const int col = colbase + ni * 16 + (lane & 15);
    const float bb = outb[col];
#pragma unroll
    for (int mi = 0; mi < 4; ++mi) {
      const int row = rowbase + mi * 16 + (lane >> 4) * 4;
#pragma unroll
      for (int rg = 0; rg < 4; ++rg)
        out[(size_t)(row + rg) * 1024 + col] = acc[mi][ni][rg] + bb;
    }
  }
}

extern "C" void kernel_launch(void* const* d_in, const int* in_sizes, int n_in,
                              void* d_out, int out_size, void* d_ws, size_t ws_size,
                              hipStream_t stream) {
  const float* enc    = (const float*)d_in[0];
  const float* pred   = (const float*)d_in[1];
  const float* enc_w  = (const float*)d_in[2];
  const float* enc_b  = (const float*)d_in[3];
  const float* pred_w = (const float*)d_in[4];
  const float* pred_b = (const float*)d_in[5];
  const float* out_w  = (const float*)d_in[6];
  const float* out_b  = (const float*)d_in[7];
  float* out = (float*)d_out;

  char* ws = (char*)d_ws;
  __bf16* E  = (__bf16*)(ws);                 // 1024*640 bf16
  __bf16* P  = (__bf16*)(ws + 1310720);       //  256*640 bf16
  __bf16* Wb = (__bf16*)(ws + 1638400);       // pre-swizzled out_w half-tiles
  __bf16* Z  = (__bf16*)(ws + 2949120);       // 256*10*2*8192 bf16, pre-swizzled

  const int zpath = (ws_size >= (size_t)86835200) ? 1 : 0;

  prep_kernel<<<dim3(370), dim3(256), 0, stream>>>(
      enc, enc_w, enc_b, pred, pred_w, pred_b, out_w, E, P, Wb, zpath);

  if (zpath) {
    zprod_kernel<<<dim3(2560), dim3(256), 0, stream>>>(E, P, Z);
    joiner_8pm<<<dim3(256), dim3(512), 0, stream>>>(Z, Wb, out_b, out);
  } else {
    joiner_fused<<<dim3(2048), dim3(512), 0, stream>>>(E, P, Wb, out_b, out);
  }
}

// Round 13
// 166.160 us; speedup vs baseline: 1.5095x; 1.5095x over previous
//
#include <hip/hip_runtime.h>
#include <cstdint>
#include <cstddef>

// RNNT joiner: logits[b,t,u,v] = sum_j tanh(E[b,t,j]+P[b,u,j]) * out_w[v,j] + out_b[v]
// B=4 T=256 U=64 D=512 J=640 V=1024.  M = 65536 rows (b,t,u), N=1024, K=640.
//
// ws layout (Z-path, R9 layouts — pass-proven):
//   E  : bf16 [1024][640]                  @ 0          (1,310,720 B)
//   P  : bf16 [ 256][640]                  @ 1,310,720  (  327,680 B)
//   Wb : bf16 [nt=4][kt=20][half=2][4096]  @ 1,638,400  (1,310,720 B)  pre-swz 128x32 tiles
//   Z  : bf16 [mt=512][kt=20][4096]        @ 2,949,120  (83,886,080 B) pre-swz 128x32 tiles
// total 86,835,200 B.  ws_size smaller -> fused fallback.

typedef __attribute__((ext_vector_type(8))) __bf16 bf16x8;
typedef __attribute__((ext_vector_type(4))) float f32x4;

// swizzle for [R][64] bf16 tiles (row stride 128B) - fallback/proj path.
__device__ __forceinline__ int swz64(int row, int kElem) {
  return (row << 6) + (kElem ^ ((row & 7) << 3));
}
// swizzle for [128][32] bf16 tiles (row stride 64B): 16B-chunk cc ^= (row&3).
__device__ __forceinline__ int swz32(int row, int kElem) {
  return (row << 5) + ((kElem & 7) | (((kElem >> 3) ^ (row & 3)) << 3));
}

__device__ __forceinline__ float fast_tanh(float x) {
  float e = __builtin_amdgcn_exp2f(x * 2.88539008177793f);  // e^(2x)
  return 1.0f - 2.0f * __builtin_amdgcn_rcpf(e + 1.0f);
}

__device__ __forceinline__ void gload_lds16(const void* g, void* l) {
  __builtin_amdgcn_global_load_lds(
      (const __attribute__((address_space(1))) void*)g,
      (__attribute__((address_space(3))) void*)l, 16, 0, 0);
}

// Barrier that is also a compiler-level memory fence (zero extra HW instrs).
__device__ __forceinline__ void wg_barrier() {
  asm volatile("" ::: "memory");
  __builtin_amdgcn_s_barrier();
  asm volatile("" ::: "memory");
}

// ---------------------------------------------------------------------------
// proj tile: C[mt*128..][nt*128..] = A[128][512] . W[128][512]^T + bias  (bf16 out)
// ---------------------------------------------------------------------------
__device__ void proj_tile(const float* __restrict__ A, const float* __restrict__ W,
                          const float* __restrict__ bias, __bf16* __restrict__ C,
                          int mt, int nt, __bf16* As, __bf16* Bs)
{
  const int tid  = threadIdx.x;
  const int r = tid & 127, half = tid >> 7;
  const int lane = tid & 63, wv = tid >> 6;
  const int wm = wv >> 1, wn = wv & 1;

  const float* arow = A + (size_t)(mt * 128 + r) * 512 + half * 32;
  const float* wrow = W + (size_t)(nt * 128 + r) * 512 + half * 32;

  f32x4 acc[4][4] = {};

  for (int k0 = 0; k0 < 512; k0 += 64) {
#pragma unroll
    for (int s = 0; s < 4; ++s) {
      f32x4 a0 = *(const f32x4*)(arow + k0 + s * 8);
      f32x4 a1 = *(const f32x4*)(arow + k0 + s * 8 + 4);
      f32x4 w0 = *(const f32x4*)(wrow + k0 + s * 8);
      f32x4 w1 = *(const f32x4*)(wrow + k0 + s * 8 + 4);
      bf16x8 za, zw;
#pragma unroll
      for (int j = 0; j < 4; ++j) {
        za[j] = (__bf16)a0[j]; za[4 + j] = (__bf16)a1[j];
        zw[j] = (__bf16)w0[j]; zw[4 + j] = (__bf16)w1[j];
      }
      const int kk = half * 32 + s * 8;
      *(bf16x8*)&As[swz64(r, kk)] = za;
      *(bf16x8*)&Bs[swz64(r, kk)] = zw;
    }
    __syncthreads();
#pragma unroll
    for (int kk = 0; kk < 2; ++kk) {
      bf16x8 af[4], bfr[4];
#pragma unroll
      for (int i = 0; i < 4; ++i) {
        af[i]  = *(const bf16x8*)&As[swz64(wm * 64 + i * 16 + (lane & 15), kk * 32 + (lane >> 4) * 8)];
        bfr[i] = *(const bf16x8*)&Bs[swz64(wn * 64 + i * 16 + (lane & 15), kk * 32 + (lane >> 4) * 8)];
      }
#pragma unroll
      for (int mi = 0; mi < 4; ++mi)
#pragma unroll
        for (int ni = 0; ni < 4; ++ni)
          acc[mi][ni] = __builtin_amdgcn_mfma_f32_16x16x32_bf16(af[mi], bfr[ni], acc[mi][ni], 0, 0, 0);
    }
    __syncthreads();
  }

  const int rowbase = mt * 128 + wm * 64;
  const int colbase = nt * 128 + wn * 64;
#pragma unroll
  for (int ni = 0; ni < 4; ++ni) {
    const int col = colbase + ni * 16 + (lane & 15);
    const float bb = bias[col];
#pragma unroll
    for (int mi = 0; mi < 4; ++mi) {
      const int row = rowbase + mi * 16 + (lane >> 4) * 4;
#pragma unroll
      for (int rg = 0; rg < 4; ++rg)
        C[(size_t)(row + rg) * 640 + col] = (__bf16)(acc[mi][ni][rg] + bb);
    }
  }
}

// ---------------------------------------------------------------------------
// prep: blocks 0..39 enc-proj, 40..49 pred-proj, 50..369 out_w conversion.
// zpath=1: Wb [nt(4)][kt(20)][half(2)][128x32 swz32].
// zpath=0: Wb [nb(8)][kt(10)][128x64 swz64]  (fallback layout).
// ---------------------------------------------------------------------------
__global__ __launch_bounds__(256) void prep_kernel(
    const float* __restrict__ enc,  const float* __restrict__ enc_w,  const float* __restrict__ enc_b,
    const float* __restrict__ pred, const float* __restrict__ pred_w, const float* __restrict__ pred_b,
    const float* __restrict__ out_w,
    __bf16* __restrict__ E, __bf16* __restrict__ P, __bf16* __restrict__ Wb, int zpath)
{
  __shared__ __align__(16) __bf16 As[128 * 64];
  __shared__ __align__(16) __bf16 Bs[128 * 64];
  const int bid = blockIdx.x;
  if (bid < 40) {
    proj_tile(enc, enc_w, enc_b, E, bid / 5, bid % 5, As, Bs);
  } else if (bid < 50) {
    proj_tile(pred, pred_w, pred_b, P, (bid - 40) / 5, (bid - 40) % 5, As, Bs);
  } else {
    const int gid = (bid - 50) * 256 + threadIdx.x;  // 81920 total (1024*80)
    const int v  = gid / 80;
    const int j8 = gid % 80;
    f32x4 w0 = *(const f32x4*)(out_w + (size_t)v * 640 + j8 * 8);
    f32x4 w1 = *(const f32x4*)(out_w + (size_t)v * 640 + j8 * 8 + 4);
    bf16x8 z;
#pragma unroll
    for (int j = 0; j < 4; ++j) { z[j] = (__bf16)w0[j]; z[4 + j] = (__bf16)w1[j]; }
    if (zpath) {
      const int nt = v >> 8;
      const int half = (v >> 7) & 1;
      const int rr = v & 127;
      const int kt = j8 >> 2;                 // 4 8-elem groups per kt
      const int kk = (j8 & 3) * 8;
      *(bf16x8*)(Wb + (((size_t)(nt * 20 + kt) * 2 + half) << 12) + swz32(rr, kk)) = z;
    } else {
      const int nb = v >> 7, rr = v & 127;
      const int kb = j8 >> 3, kk = (j8 & 7) * 8;
      *(bf16x8*)(Wb + ((size_t)(nb * 10 + kb) << 13) + swz64(rr, kk)) = z;
    }
  }
}

// ---------------------------------------------------------------------------
// zprod: Z[mt][kt][4096] = tanh(E+P) for M-tile mt (128 rows), K-tile kt (32),
// written pre-swizzled (swz32) with LINEAR stores; source k inverted
// (XOR swizzle is an involution).  grid = 512*20 = 10240, 256 thr.
// ---------------------------------------------------------------------------
__global__ __launch_bounds__(256) void zprod_kernel(
    const __bf16* __restrict__ E, const __bf16* __restrict__ P,
    __bf16* __restrict__ Z)
{
  const int bid = blockIdx.x;
  const int mt = bid / 20, kt = bid % 20;
  __bf16* zdst = Z + ((size_t)bid << 12);      // 4096 elems per (mt,kt)

#pragma unroll
  for (int c = 0; c < 2; ++c) {
    const int o = c * 2048 + threadIdx.x * 8;  // linear offset in 4096-elem tile
    const int r = o >> 5;                      // row 0..127
    const int cc = (o >> 3) & 3;               // stored 16B chunk
    const int k = kt * 32 + ((cc ^ (r & 3)) << 3);  // original k (inverse swz32)
    const int grow = mt * 128 + r;             // global M-row = ((b*256+t)*64+u)
    const __bf16* ep = E + (size_t)(grow >> 6) * 640 + k;
    const __bf16* pp = P + (size_t)(((grow >> 14) << 6) | (grow & 63)) * 640 + k;
    bf16x8 e8 = *(const bf16x8*)ep;
    bf16x8 p8 = *(const bf16x8*)pp;
    bf16x8 z;
#pragma unroll
    for (int j = 0; j < 8; ++j)
      z[j] = (__bf16)fast_tanh((float)e8[j] + (float)p8[j]);
    *(bf16x8*)&zdst[o] = z;
  }
}

// ---------------------------------------------------------------------------
// main (Z-path): pure bf16 GEMM, fine 2-phase split + COUNTED vmcnt(2).
// Tile 128(M) x 256(N), BK=32, 20 K-tiles, 512 thr = 8 waves (2M x 4N),
// wave-tile 64x64 (acc 64 VGPR).  LDS dbuf 48 KB -> 2-3 blocks/CU (epilogue
// stores / prologue of a block overlap co-resident blocks' MFMA, m114; no
// in-kernel stores touch the counted ledger until block end).
// Per K-tile t (buffers d=t&1):
//   Ph0: stage A(t+1),B0(t+1) -> d^1;  vmcnt(2)  [drains tile-t's 3 ops,
//        staged one full tile earlier; t+1's 2 stay in flight];
//        wg_barrier (publish t);  ds_read af[0..3], bf[0..1];  lgkm(0);
//        8 MFMA (mi x ni01, setprio).
//   Ph1: ds_read bf[2..3];  stage B1(t+1);  lgkm(0);  8 MFMA (mi x ni23);
//        wg_barrier (tail: all waves' reads of d retired before next write).
// Grid 2048 = 512 mt x 4 nt, XCD-swizzled; consecutive bids share mt -> L2.
// ---------------------------------------------------------------------------
__global__ __launch_bounds__(512, 4) void joiner_fine(
    const __bf16* __restrict__ Z, const __bf16* __restrict__ Wb,
    const float* __restrict__ outb, float* __restrict__ out)
{
  __shared__ __align__(16) __bf16 As[2][4096];   // 16 KB
  __shared__ __align__(16) __bf16 Bs[2][8192];   // 32 KB
  const int wg = blockIdx.x;
  const int bid = (wg & 7) * 256 + (wg >> 3);    // XCD-contiguous chunks
  const int mt = bid >> 2, nt = bid & 3;
  const int tid = threadIdx.x;
  const int lane = tid & 63, wv = tid >> 6;
  const int wm = wv >> 2, wn = wv & 3;           // 2 x 4 wave grid
  const int q = lane & 15;
  const int chunk = (((lane >> 4) ^ (q & 3)) << 3);

  const __bf16* zsrc = Z  + (size_t)mt * 81920;  // 20 * 4096
  const __bf16* wsrc = Wb + (size_t)nt * 163840; // 20 * 2 * 4096

  const int abase = (wm * 64 + q) * 32 + chunk;  // + mi*512
  const int bbase = (wn * 64 + q) * 32 + chunk;  // + ni*512

  f32x4 acc[4][4] = {};
  const int wo = wv * 512;

  // ---- prologue: tile 0's three ops, in ledger order [A, B0, B1] ----
  gload_lds16(zsrc + wo + lane * 8,        &As[0][wo]);
  gload_lds16(wsrc + wo + lane * 8,        &Bs[0][wo]);
  gload_lds16(wsrc + 4096 + wo + lane * 8, &Bs[0][4096 + wo]);

  for (int t = 0; t < 20; ++t) {
    const int d = t & 1;
    const int nd = d ^ 1;
    bf16x8 af[4], b01[2], b23[2];

    // ===== Ph0 =====
    if (t < 19) {
      gload_lds16(zsrc + (t + 1) * 4096 + wo + lane * 8, &As[nd][wo]);   // A(t+1)
      gload_lds16(wsrc + (t + 1) * 8192 + wo + lane * 8, &Bs[nd][wo]);   // B0(t+1)
      asm volatile("s_waitcnt vmcnt(2)" ::: "memory");   // drain tile t only
    } else {
      asm volatile("s_waitcnt vmcnt(0)" ::: "memory");
    }
    wg_barrier();                                        // publish tile t
#pragma unroll
    for (int mi = 0; mi < 4; ++mi)
      af[mi] = *(const bf16x8*)&As[d][abase + mi * 512];
#pragma unroll
    for (int ni = 0; ni < 2; ++ni)
      b01[ni] = *(const bf16x8*)&Bs[d][bbase + ni * 512];
    asm volatile("s_waitcnt lgkmcnt(0)" ::: "memory");
    __builtin_amdgcn_sched_barrier(0);
    __builtin_amdgcn_s_setprio(1);
#pragma unroll
    for (int mi = 0; mi < 4; ++mi)
#pragma unroll
      for (int ni = 0; ni < 2; ++ni)
        acc[mi][ni] = __builtin_amdgcn_mfma_f32_16x16x32_bf16(af[mi], b01[ni], acc[mi][ni], 0, 0, 0);
    __builtin_amdgcn_s_setprio(0);

    // ===== Ph1 =====
#pragma unroll
    for (int ni = 0; ni < 2; ++ni)
      b23[ni] = *(const bf16x8*)&Bs[d][bbase + (2 + ni) * 512];
    if (t < 19)
      gload_lds16(wsrc + (t + 1) * 8192 + 4096 + wo + lane * 8, &Bs[nd][4096 + wo]);  // B1(t+1)
    asm volatile("s_waitcnt lgkmcnt(0)" ::: "memory");
    __builtin_amdgcn_sched_barrier(0);
    __builtin_amdgcn_s_setprio(1);
#pragma unroll
    for (int mi = 0; mi < 4; ++mi)
#pragma unroll
      for (int ni = 0; ni < 2; ++ni)
        acc[mi][2 + ni] = __builtin_amdgcn_mfma_f32_16x16x32_bf16(af[mi], b23[ni], acc[mi][2 + ni], 0, 0, 0);
    __builtin_amdgcn_s_setprio(0);
    wg_barrier();                                        // tail: reads of d retired
  }

  // epilogue: bias + store (64B-coalesced segments)
  const int rowbase = (mt << 7) + wm * 64;
  const int colbase = (nt << 8) + wn * 64;
#pragma unroll
  for (int ni = 0; ni < 4; ++ni) {
    const int col = colbase + ni * 16 + q;
    const float bb = outb[col];
#pragma unroll
    for (int mi = 0; mi < 4; ++mi) {
      const int row = rowbase + mi * 16 + (lane >> 4) * 4;
#pragma unroll
      for (int rg = 0; rg < 4; ++rg)
        out[(size_t)(row + rg) * 1024 + col] = acc[mi][ni][rg] + bb;
    }
  }
}

// ---------------------------------------------------------------------------
// Fallback (small ws): R5 fused kernel, Wb in [8][10][128x64 swz64] layout.
// ---------------------------------------------------------------------------
__global__ __launch_bounds__(512, 4) void joiner_fused(
    const __bf16* __restrict__ E, const __bf16* __restrict__ P,
    const __bf16* __restrict__ Wb, const float* __restrict__ outb,
    float* __restrict__ out)
{
  __shared__ __align__(16) __bf16 As[8192];
  __shared__ __align__(16) __bf16 Bs[2][16384];
  const int tid = threadIdx.x;
  const int nt = blockIdx.x & 3;
  const int mt = blockIdx.x >> 2;
  const int row0 = mt << 7;
  const int b  = row0 >> 14;
  const int t0 = (row0 >> 6) & 255;
  const int ar = tid & 127, h = tid >> 7;
  const int lane = tid & 63, wv = tid >> 6;
  const int wm = wv >> 2, wn = wv & 3;

  const __bf16* ep = E + (size_t)((b << 8) + t0 + (ar >> 6)) * 640 + h * 16;
  const __bf16* pp = P + (size_t)((b << 6) + (ar & 63)) * 640 + h * 16;

  f32x4 acc[4][4] = {};
  bf16x8 eA[2], pA[2];

  auto stageB2 = [&](int kt, __bf16* dst) {
#pragma unroll
    for (int c = 0; c < 4; ++c) {
      const int blk = nt * 2 + (c >> 1);
      const int inoff = (c & 1) * 4096 + wv * 512;
      gload_lds16(Wb + ((size_t)(blk * 10 + kt) << 13) + inoff + lane * 8,
                  dst + (c >> 1) * 8192 + inoff);
    }
  };
  auto loadEP = [&](int k0) {
#pragma unroll
    for (int c = 0; c < 2; ++c) {
      eA[c] = *(const bf16x8*)(ep + k0 + c * 8);
      pA[c] = *(const bf16x8*)(pp + k0 + c * 8);
    }
  };
  auto writeA = [&]() {
#pragma unroll
    for (int c = 0; c < 2; ++c) {
      bf16x8 z;
#pragma unroll
      for (int j = 0; j < 8; ++j)
        z[j] = (__bf16)fast_tanh((float)eA[c][j] + (float)pA[c][j]);
      *(bf16x8*)&As[swz64(ar, h * 16 + c * 8)] = z;
    }
  };
  auto compute = [&](const __bf16* Bsc) {
#pragma unroll
    for (int kk = 0; kk < 2; ++kk) {
      bf16x8 af[4], bfr[4];
#pragma unroll
      for (int i = 0; i < 4; ++i) {
        af[i]  = *(const bf16x8*)&As[swz64(wm * 64 + i * 16 + (lane & 15), kk * 32 + (lane >> 4) * 8)];
        bfr[i] = *(const bf16x8*)&Bsc[swz64(wn * 64 + i * 16 + (lane & 15), kk * 32 + (lane >> 4) * 8)];
      }
      asm volatile("s_waitcnt lgkmcnt(0)" ::: "memory");
      __builtin_amdgcn_sched_barrier(0);
      __builtin_amdgcn_s_setprio(1);
#pragma unroll
      for (int mi = 0; mi < 4; ++mi)
#pragma unroll
        for (int ni = 0; ni < 4; ++ni)
          acc[mi][ni] = __builtin_amdgcn_mfma_f32_16x16x32_bf16(af[mi], bfr[ni], acc[mi][ni], 0, 0, 0);
      __builtin_amdgcn_s_setprio(0);
    }
  };

  stageB2(0, Bs[0]);
  loadEP(0);
  writeA();
  asm volatile("s_waitcnt vmcnt(0) lgkmcnt(0)" ::: "memory");
  wg_barrier();

  for (int kt = 0; kt < 9; ++kt) {
    const int cur = kt & 1;
    stageB2(kt + 1, Bs[cur ^ 1]);
    loadEP((kt + 1) << 6);
    compute(Bs[cur]);
    wg_barrier();
    __builtin_amdgcn_sched_barrier(0);
    writeA();
    asm volatile("s_waitcnt lgkmcnt(0)" ::: "memory");
    wg_barrier();
  }
  compute(Bs[1]);

  const int rowbase = row0 + wm * 64;
  const int colbase = (nt << 8) + wn * 64;
#pragma unroll
  for (int ni = 0; ni < 4; ++ni) {
    const int col = colbase + ni * 16 + (lane & 15);
    const float bb = outb[col];
#pragma unroll
    for (int mi = 0; mi < 4; ++mi) {
      const int row = rowbase + mi * 16 + (lane >> 4) * 4;
#pragma unroll
      for (int rg = 0; rg < 4; ++rg)
        out[(size_t)(row + rg) * 1024 + col] = acc[mi][ni][rg] + bb;
    }
  }
}

extern "C" void kernel_launch(void* const* d_in, const int* in_sizes, int n_in,
                              void* d_out, int out_size, void* d_ws, size_t ws_size,
                              hipStream_t stream) {
  const float* enc    = (const float*)d_in[0];
  const float* pred   = (const float*)d_in[1];
  const float* enc_w  = (const float*)d_in[2];
  const float* enc_b  = (const float*)d_in[3];
  const float* pred_w = (const float*)d_in[4];
  const float* pred_b = (const float*)d_in[5];
  const float* out_w  = (const float*)d_in[6];
  const float* out_b  = (const float*)d_in[7];
  float* out = (float*)d_out;

  char* ws = (char*)d_ws;
  __bf16* E  = (__bf16*)(ws);                 // 1024*640 bf16
  __bf16* P  = (__bf16*)(ws + 1310720);       //  256*640 bf16
  __bf16* Wb = (__bf16*)(ws + 1638400);       // pre-swizzled out_w tiles
  __bf16* Z  = (__bf16*)(ws + 2949120);       // 512*20*4096 bf16, pre-swizzled

  const int zpath = (ws_size >= (size_t)86835200) ? 1 : 0;

  prep_kernel<<<dim3(370), dim3(256), 0, stream>>>(
      enc, enc_w, enc_b, pred, pred_w, pred_b, out_w, E, P, Wb, zpath);

  if (zpath) {
    zprod_kernel<<<dim3(10240), dim3(256), 0, stream>>>(E, P, Z);
    joiner_fine<<<dim3(2048), dim3(512), 0, stream>>>(Z, Wb, out_b, out);
  } else {
    joiner_fused<<<dim3(2048), dim3(512), 0, stream>>>(E, P, Wb, out_b, out);
  }
}

// Round 14
// 155.805 us; speedup vs baseline: 1.6098x; 1.0665x over previous
//
#include <hip/hip_runtime.h>
#include <cstdint>
#include <cstddef>

// RNNT joiner: logits[b,t,u,v] = sum_j tanh(E[b,t,j]+P[b,u,j]) * out_w[v,j] + out_b[v]
// B=4 T=256 U=64 D=512 J=640 V=1024.  M = 65536 rows (b,t,u), N=1024, K=640.
//
// ws layout (Z-path, R8 layouts — pass-proven):
//   E  : bf16 [1024][640]                  @ 0          (1,310,720 B)
//   P  : bf16 [ 256][640]                  @ 1,310,720  (  327,680 B)
//   Wb : bf16 [nt=4][kt=10][half=2][8192]  @ 1,638,400  (1,310,720 B)  pre-swz 128x64 half-tiles
//   Z  : bf16 [mt=256][kt=10][half=2][8192]@ 2,949,120  (83,886,080 B) pre-swz 128x64 half-tiles
// total 86,835,200 B.  ws_size smaller -> fused fallback.

typedef __attribute__((ext_vector_type(8))) __bf16 bf16x8;
typedef __attribute__((ext_vector_type(4))) float f32x4;

// XOR swizzle within a [128][64] bf16 half-tile (row stride 128B).
__device__ __forceinline__ int swz64(int row, int kElem) {
  return (row << 6) + (kElem ^ ((row & 7) << 3));
}

__device__ __forceinline__ float fast_tanh(float x) {
  float e = __builtin_amdgcn_exp2f(x * 2.88539008177793f);  // e^(2x)
  return 1.0f - 2.0f * __builtin_amdgcn_rcpf(e + 1.0f);
}

__device__ __forceinline__ void gload_lds16(const void* g, void* l) {
  __builtin_amdgcn_global_load_lds(
      (const __attribute__((address_space(1))) void*)g,
      (__attribute__((address_space(3))) void*)l, 16, 0, 0);
}

// Barrier that is also a compiler-level memory fence (zero extra HW instrs).
__device__ __forceinline__ void wg_barrier() {
  asm volatile("" ::: "memory");
  __builtin_amdgcn_s_barrier();
  asm volatile("" ::: "memory");
}

// ---------------------------------------------------------------------------
// proj tile: C[mt*128..][nt*128..] = A[128][512] . W[128][512]^T + bias  (bf16 out)
// ---------------------------------------------------------------------------
__device__ void proj_tile(const float* __restrict__ A, const float* __restrict__ W,
                          const float* __restrict__ bias, __bf16* __restrict__ C,
                          int mt, int nt, __bf16* As, __bf16* Bs)
{
  const int tid  = threadIdx.x;
  const int r = tid & 127, half = tid >> 7;
  const int lane = tid & 63, wv = tid >> 6;
  const int wm = wv >> 1, wn = wv & 1;

  const float* arow = A + (size_t)(mt * 128 + r) * 512 + half * 32;
  const float* wrow = W + (size_t)(nt * 128 + r) * 512 + half * 32;

  f32x4 acc[4][4] = {};

  for (int k0 = 0; k0 < 512; k0 += 64) {
#pragma unroll
    for (int s = 0; s < 4; ++s) {
      f32x4 a0 = *(const f32x4*)(arow + k0 + s * 8);
      f32x4 a1 = *(const f32x4*)(arow + k0 + s * 8 + 4);
      f32x4 w0 = *(const f32x4*)(wrow + k0 + s * 8);
      f32x4 w1 = *(const f32x4*)(wrow + k0 + s * 8 + 4);
      bf16x8 za, zw;
#pragma unroll
      for (int j = 0; j < 4; ++j) {
        za[j] = (__bf16)a0[j]; za[4 + j] = (__bf16)a1[j];
        zw[j] = (__bf16)w0[j]; zw[4 + j] = (__bf16)w1[j];
      }
      const int kk = half * 32 + s * 8;
      *(bf16x8*)&As[swz64(r, kk)] = za;
      *(bf16x8*)&Bs[swz64(r, kk)] = zw;
    }
    __syncthreads();
#pragma unroll
    for (int kk = 0; kk < 2; ++kk) {
      bf16x8 af[4], bfr[4];
#pragma unroll
      for (int i = 0; i < 4; ++i) {
        af[i]  = *(const bf16x8*)&As[swz64(wm * 64 + i * 16 + (lane & 15), kk * 32 + (lane >> 4) * 8)];
        bfr[i] = *(const bf16x8*)&Bs[swz64(wn * 64 + i * 16 + (lane & 15), kk * 32 + (lane >> 4) * 8)];
      }
#pragma unroll
      for (int mi = 0; mi < 4; ++mi)
#pragma unroll
        for (int ni = 0; ni < 4; ++ni)
          acc[mi][ni] = __builtin_amdgcn_mfma_f32_16x16x32_bf16(af[mi], bfr[ni], acc[mi][ni], 0, 0, 0);
    }
    __syncthreads();
  }

  const int rowbase = mt * 128 + wm * 64;
  const int colbase = nt * 128 + wn * 64;
#pragma unroll
  for (int ni = 0; ni < 4; ++ni) {
    const int col = colbase + ni * 16 + (lane & 15);
    const float bb = bias[col];
#pragma unroll
    for (int mi = 0; mi < 4; ++mi) {
      const int row = rowbase + mi * 16 + (lane >> 4) * 4;
#pragma unroll
      for (int rg = 0; rg < 4; ++rg)
        C[(size_t)(row + rg) * 640 + col] = (__bf16)(acc[mi][ni][rg] + bb);
    }
  }
}

// ---------------------------------------------------------------------------
// prep: blocks 0..39 enc-proj, 40..49 pred-proj, 50..369 out_w conversion.
// zpath=1: Wb [nt(4)][kt(10)][half(2)][128x64 swz64].
// zpath=0: Wb [nb(8)][kt(10)][128x64 swz64]  (fallback layout).
// ---------------------------------------------------------------------------
__global__ __launch_bounds__(256) void prep_kernel(
    const float* __restrict__ enc,  const float* __restrict__ enc_w,  const float* __restrict__ enc_b,
    const float* __restrict__ pred, const float* __restrict__ pred_w, const float* __restrict__ pred_b,
    const float* __restrict__ out_w,
    __bf16* __restrict__ E, __bf16* __restrict__ P, __bf16* __restrict__ Wb, int zpath)
{
  __shared__ __align__(16) __bf16 As[128 * 64];
  __shared__ __align__(16) __bf16 Bs[128 * 64];
  const int bid = blockIdx.x;
  if (bid < 40) {
    proj_tile(enc, enc_w, enc_b, E, bid / 5, bid % 5, As, Bs);
  } else if (bid < 50) {
    proj_tile(pred, pred_w, pred_b, P, (bid - 40) / 5, (bid - 40) % 5, As, Bs);
  } else {
    const int gid = (bid - 50) * 256 + threadIdx.x;  // 81920 total (1024*80)
    const int v  = gid / 80;
    const int j8 = gid % 80;
    f32x4 w0 = *(const f32x4*)(out_w + (size_t)v * 640 + j8 * 8);
    f32x4 w1 = *(const f32x4*)(out_w + (size_t)v * 640 + j8 * 8 + 4);
    bf16x8 z;
#pragma unroll
    for (int j = 0; j < 4; ++j) { z[j] = (__bf16)w0[j]; z[4 + j] = (__bf16)w1[j]; }
    if (zpath) {
      const int nt = v >> 8, vv = v & 255;
      const int half = vv >> 7, rr = vv & 127;
      const int kt = j8 >> 3, kk = (j8 & 7) * 8;
      *(bf16x8*)(Wb + (((size_t)(nt * 10 + kt) * 2 + half) << 13) + swz64(rr, kk)) = z;
    } else {
      const int nb = v >> 7, rr = v & 127;
      const int kb = j8 >> 3, kk = (j8 & 7) * 8;
      *(bf16x8*)(Wb + ((size_t)(nb * 10 + kb) << 13) + swz64(rr, kk)) = z;
    }
  }
}

// ---------------------------------------------------------------------------
// zprod: Z[mt][kt][half][8192] = tanh(E+P), pre-swizzled half-tiles, LINEAR
// stores (swizzle inverted at source index).  grid = 2560 (mt*10+kt), 256 thr.
// ---------------------------------------------------------------------------
__global__ __launch_bounds__(256) void zprod_kernel(
    const __bf16* __restrict__ E, const __bf16* __restrict__ P,
    __bf16* __restrict__ Z)
{
  const int bid = blockIdx.x;
  const int mt = bid / 10, kt = bid % 10;
  __bf16* zdst = Z + ((size_t)bid << 14);      // 16384 elems per (mt,kt)

#pragma unroll
  for (int c = 0; c < 8; ++c) {
    const int o = c * 2048 + threadIdx.x * 8;  // linear offset in 16K-elem block
    const int half = o >> 13, oo = o & 8191;
    const int rr = oo >> 6;
    const int r = half * 128 + rr;             // tile row 0..255
    const int k = kt * 64 + ((oo & 63) ^ ((rr & 7) << 3));
    const int grow = mt * 256 + r;             // global M-row
    const __bf16* ep = E + (size_t)(grow >> 6) * 640 + k;
    const __bf16* pp = P + (size_t)(((grow >> 14) << 6) | (grow & 63)) * 640 + k;
    bf16x8 e8 = *(const bf16x8*)ep;
    bf16x8 p8 = *(const bf16x8*)pp;
    bf16x8 z;
#pragma unroll
    for (int j = 0; j < 8; ++j)
      z[j] = (__bf16)fast_tanh((float)e8[j] + (float)p8[j]);
    *(bf16x8*)&zdst[o] = z;
  }
}

// ---------------------------------------------------------------------------
// main (Z-path): R8's 8-phase GEMM + FRAGMENT READ-AHEAD (LDS || MFMA overlap).
// Tile 256x256, BK=64, 10 K-tiles, 512 thr = 8 waves (2M x 4N), wave-tile
// 128x64, interleaved frags.  Stage stream & vmcnt(6) ledger identical to R8.
// Read schedule (counted lgkm; DS completes in order):
//   P0: stage A1(t+1); vmcnt(6); BAR; read bl,bh; lgkm(4)[afl+bl done, bh out];
//       MFMA(afl x bl).  afl was read at (t-1)P3 and retired under its MFMA.
//   P1: issue afh(8); stage A0(t+2); BAR; lgkm(8)[bh done, afh out];
//       MFMA(afl x bh).
//   P2: stage B0(t+2); BAR; lgkm(0)[afh done]; MFMA(afh x bh).
//   P3: stage B1(t+2); issue afl(t+1)(8); MFMA(afh x bl); BAR.
// Soundness: every read-ahead source was vmcnt-drained and barrier-published
// >= 1 phase before its read; every LDS WAR separated by >= 2 barriers.
// Only bl's 4 reads remain on the critical path per K-tile.
// ---------------------------------------------------------------------------
__global__ __launch_bounds__(512, 2) void joiner_8pr(
    const __bf16* __restrict__ Z, const __bf16* __restrict__ Wb,
    const float* __restrict__ outb, float* __restrict__ out)
{
  __shared__ __align__(16) __bf16 As[2][2][8192];   // [dbuf][half][128x64]
  __shared__ __align__(16) __bf16 Bs[2][2][8192];
  const int wg = blockIdx.x;
  const int bid = (wg & 7) * 128 + (wg >> 3);       // XCD-contiguous chunks
  const int mt = bid >> 2, nt = bid & 3;
  const int tid = threadIdx.x;
  const int lane = tid & 63, wv = tid >> 6;
  const int wm = wv >> 2, wn = wv & 3;              // 2 x 4 wave grid

  const int rb  = wm * 16 + (lane & 15);
  const int cb  = wn * 16 + (lane & 15);
  const int kb8 = (lane >> 4) * 8;

  const __bf16* zsrc = Z  + ((size_t)(mt * 20) << 13);  // [10][2][8192]
  const __bf16* wsrc = Wb + ((size_t)(nt * 20) << 13);

  f32x4 acc[8][4] = {};
  bf16x8 afl[4][2], afh[4][2], bl[2][2], bh[2][2];

  auto stA = [&](int kt, int half) {
    __bf16* dst = &As[kt & 1][half][wv * 512];
    const __bf16* src = zsrc + (((size_t)kt * 2 + half) << 13) + wv * 512 + lane * 8;
    gload_lds16(src, dst);
    gload_lds16(src + 4096, dst + 4096);
  };
  auto stB = [&](int kt, int half) {
    __bf16* dst = &Bs[kt & 1][half][wv * 512];
    const __bf16* src = wsrc + (((size_t)kt * 2 + half) << 13) + wv * 512 + lane * 8;
    gload_lds16(src, dst);
    gload_lds16(src + 4096, dst + 4096);
  };
  auto rdAfl = [&](const __bf16* A0) {
#pragma unroll
    for (int f = 0; f < 4; ++f)
#pragma unroll
      for (int kk = 0; kk < 2; ++kk)
        afl[f][kk] = *(const bf16x8*)&A0[swz64(f * 32 + rb, kk * 32 + kb8)];
  };
  auto rdAfh = [&](const __bf16* A1) {
#pragma unroll
    for (int f = 0; f < 4; ++f)
#pragma unroll
      for (int kk = 0; kk < 2; ++kk)
        afh[f][kk] = *(const bf16x8*)&A1[swz64(f * 32 + rb, kk * 32 + kb8)];
  };

  // ---- prologue: stage stream s=0..6 = T0{A0,B0,B1,A1} T1{A0,B0,B1} ----
  stA(0, 0); stB(0, 0); stB(0, 1); stA(0, 1);
  stA(1, 0); stB(1, 0); stB(1, 1);
  asm volatile("s_waitcnt vmcnt(6)" ::: "memory");  // all of tile 0 landed
  wg_barrier();
  rdAfl(&As[0][0][0]);                              // read-ahead afl(0)
  __builtin_amdgcn_sched_barrier(0);

#pragma unroll
  for (int t = 0; t < 10; ++t) {
    const int d = t & 1;
    const __bf16* A1 = &As[d][1][0];
    const __bf16* B0 = &Bs[d][0][0];
    const __bf16* B1 = &Bs[d][1][0];

    // ===== P0: stage A1(t+1); vmcnt; BAR; read bl,bh; lgkm(4); MFMA f0-3 x g0-1
    if (t < 9) stA(t + 1, 1);
    if (t == 9) asm volatile("s_waitcnt vmcnt(0)" ::: "memory");
    else        asm volatile("s_waitcnt vmcnt(6)" ::: "memory");
    wg_barrier();
#pragma unroll
    for (int g = 0; g < 2; ++g)
#pragma unroll
      for (int kk = 0; kk < 2; ++kk)
        bl[g][kk] = *(const bf16x8*)&B0[swz64(g * 64 + cb, kk * 32 + kb8)];
    __builtin_amdgcn_sched_barrier(0);     // pin order: bl before bh
#pragma unroll
    for (int g = 0; g < 2; ++g)
#pragma unroll
      for (int kk = 0; kk < 2; ++kk)
        bh[g][kk] = *(const bf16x8*)&B1[swz64(g * 64 + cb, kk * 32 + kb8)];
    asm volatile("s_waitcnt lgkmcnt(4)" ::: "memory");  // afl+bl done; bh in flight
    __builtin_amdgcn_sched_barrier(0);
    __builtin_amdgcn_s_setprio(1);
#pragma unroll
    for (int kk = 0; kk < 2; ++kk)
#pragma unroll
      for (int f = 0; f < 4; ++f)
#pragma unroll
        for (int g = 0; g < 2; ++g)
          acc[f][g] = __builtin_amdgcn_mfma_f32_16x16x32_bf16(afl[f][kk], bl[g][kk], acc[f][g], 0, 0, 0);
    __builtin_amdgcn_s_setprio(0);
    wg_barrier();

    // ===== P1: issue afh(8); stage A0(t+2); BAR; lgkm(8); MFMA f0-3 x g2-3
    rdAfh(A1);
    __builtin_amdgcn_sched_barrier(0);     // pin afh issue point
    if (t < 8) stA(t + 2, 0);
    wg_barrier();
    asm volatile("s_waitcnt lgkmcnt(8)" ::: "memory");  // bh done; afh in flight
    __builtin_amdgcn_sched_barrier(0);
    __builtin_amdgcn_s_setprio(1);
#pragma unroll
    for (int kk = 0; kk < 2; ++kk)
#pragma unroll
      for (int f = 0; f < 4; ++f)
#pragma unroll
        for (int g = 0; g < 2; ++g)
          acc[f][2 + g] = __builtin_amdgcn_mfma_f32_16x16x32_bf16(afl[f][kk], bh[g][kk], acc[f][2 + g], 0, 0, 0);
    __builtin_amdgcn_s_setprio(0);
    wg_barrier();

    // ===== P2: stage B0(t+2); BAR; lgkm(0); MFMA f4-7 x g2-3
    if (t < 8) stB(t + 2, 0);
    wg_barrier();
    asm volatile("s_waitcnt lgkmcnt(0)" ::: "memory");  // afh done
    __builtin_amdgcn_sched_barrier(0);
    __builtin_amdgcn_s_setprio(1);
#pragma unroll
    for (int kk = 0; kk < 2; ++kk)
#pragma unroll
      for (int f = 0; f < 4; ++f)
#pragma unroll
        for (int g = 0; g < 2; ++g)
          acc[4 + f][2 + g] = __builtin_amdgcn_mfma_f32_16x16x32_bf16(afh[f][kk], bh[g][kk], acc[4 + f][2 + g], 0, 0, 0);
    __builtin_amdgcn_s_setprio(0);
    wg_barrier();

    // ===== P3: stage B1(t+2); read-ahead afl(t+1); MFMA f4-7 x g0-1; BAR
    if (t < 8) stB(t + 2, 1);
    if (t < 9) rdAfl(&As[(t + 1) & 1][0][0]);          // retires under this MFMA
    __builtin_amdgcn_sched_barrier(0);
    __builtin_amdgcn_s_setprio(1);
#pragma unroll
    for (int kk = 0; kk < 2; ++kk)
#pragma unroll
      for (int f = 0; f < 4; ++f)
#pragma unroll
        for (int g = 0; g < 2; ++g)
          acc[4 + f][g] = __builtin_amdgcn_mfma_f32_16x16x32_bf16(afh[f][kk], bl[g][kk], acc[4 + f][g], 0, 0, 0);
    __builtin_amdgcn_s_setprio(0);
    wg_barrier();   // tile boundary
  }

  // ---- epilogue: bias + store ----
  const int rowbase = (mt << 8) + wm * 16 + (lane >> 4) * 4;
  const int colbase = (nt << 8) + wn * 16 + (lane & 15);
#pragma unroll
  for (int g = 0; g < 4; ++g) {
    const int col = colbase + g * 64;
    const float bb = outb[col];
#pragma unroll
    for (int f = 0; f < 8; ++f) {
      const int row = rowbase + f * 32;
#pragma unroll
      for (int rg = 0; rg < 4; ++rg)
        out[(size_t)(row + rg) * 1024 + col] = acc[f][g][rg] + bb;
    }
  }
}

// ---------------------------------------------------------------------------
// Fallback (small ws): R5 fused kernel, Wb in [8][10][128x64 swz64] layout.
// ---------------------------------------------------------------------------
__global__ __launch_bounds__(512, 4) void joiner_fused(
    const __bf16* __restrict__ E, const __bf16* __restrict__ P,
    const __bf16* __restrict__ Wb, const float* __restrict__ outb,
    float* __restrict__ out)
{
  __shared__ __align__(16) __bf16 As[8192];
  __shared__ __align__(16) __bf16 Bs[2][16384];
  const int tid = threadIdx.x;
  const int nt = blockIdx.x & 3;
  const int mt = blockIdx.x >> 2;
  const int row0 = mt << 7;
  const int b  = row0 >> 14;
  const int t0 = (row0 >> 6) & 255;
  const int ar = tid & 127, h = tid >> 7;
  const int lane = tid & 63, wv = tid >> 6;
  const int wm = wv >> 2, wn = wv & 3;

  const __bf16* ep = E + (size_t)((b << 8) + t0 + (ar >> 6)) * 640 + h * 16;
  const __bf16* pp = P + (size_t)((b << 6) + (ar & 63)) * 640 + h * 16;

  f32x4 acc[4][4] = {};
  bf16x8 eA[2], pA[2];

  auto stageB2 = [&](int kt, __bf16* dst) {
#pragma unroll
    for (int c = 0; c < 4; ++c) {
      const int blk = nt * 2 + (c >> 1);
      const int inoff = (c & 1) * 4096 + wv * 512;
      gload_lds16(Wb + ((size_t)(blk * 10 + kt) << 13) + inoff + lane * 8,
                  dst + (c >> 1) * 8192 + inoff);
    }
  };
  auto loadEP = [&](int k0) {
#pragma unroll
    for (int c = 0; c < 2; ++c) {
      eA[c] = *(const bf16x8*)(ep + k0 + c * 8);
      pA[c] = *(const bf16x8*)(pp + k0 + c * 8);
    }
  };
  auto writeA = [&]() {
#pragma unroll
    for (int c = 0; c < 2; ++c) {
      bf16x8 z;
#pragma unroll
      for (int j = 0; j < 8; ++j)
        z[j] = (__bf16)fast_tanh((float)eA[c][j] + (float)pA[c][j]);
      *(bf16x8*)&As[swz64(ar, h * 16 + c * 8)] = z;
    }
  };
  auto compute = [&](const __bf16* Bsc) {
#pragma unroll
    for (int kk = 0; kk < 2; ++kk) {
      bf16x8 af[4], bfr[4];
#pragma unroll
      for (int i = 0; i < 4; ++i) {
        af[i]  = *(const bf16x8*)&As[swz64(wm * 64 + i * 16 + (lane & 15), kk * 32 + (lane >> 4) * 8)];
        bfr[i] = *(const bf16x8*)&Bsc[swz64(wn * 64 + i * 16 + (lane & 15), kk * 32 + (lane >> 4) * 8)];
      }
      asm volatile("s_waitcnt lgkmcnt(0)" ::: "memory");
      __builtin_amdgcn_sched_barrier(0);
      __builtin_amdgcn_s_setprio(1);
#pragma unroll
      for (int mi = 0; mi < 4; ++mi)
#pragma unroll
        for (int ni = 0; ni < 4; ++ni)
          acc[mi][ni] = __builtin_amdgcn_mfma_f32_16x16x32_bf16(af[mi], bfr[ni], acc[mi][ni], 0, 0, 0);
      __builtin_amdgcn_s_setprio(0);
    }
  };

  stageB2(0, Bs[0]);
  loadEP(0);
  writeA();
  asm volatile("s_waitcnt vmcnt(0) lgkmcnt(0)" ::: "memory");
  wg_barrier();

  for (int kt = 0; kt < 9; ++kt) {
    const int cur = kt & 1;
    stageB2(kt + 1, Bs[cur ^ 1]);
    loadEP((kt + 1) << 6);
    compute(Bs[cur]);
    wg_barrier();
    __builtin_amdgcn_sched_barrier(0);
    writeA();
    asm volatile("s_waitcnt lgkmcnt(0)" ::: "memory");
    wg_barrier();
  }
  compute(Bs[1]);

  const int rowbase = row0 + wm * 64;
  const int colbase = (nt << 8) + wn * 64;
#pragma unroll
  for (int ni = 0; ni < 4; ++ni) {
    const int col = colbase + ni * 16 + (lane & 15);
    const float bb = outb[col];
#pragma unroll
    for (int mi = 0; mi < 4; ++mi) {
      const int row = rowbase + mi * 16 + (lane >> 4) * 4;
#pragma unroll
      for (int rg = 0; rg < 4; ++rg)
        out[(size_t)(row + rg) * 1024 + col] = acc[mi][ni][rg] + bb;
    }
  }
}

extern "C" void kernel_launch(void* const* d_in, const int* in_sizes, int n_in,
                              void* d_out, int out_size, void* d_ws, size_t ws_size,
                              hipStream_t stream) {
  const float* enc    = (const float*)d_in[0];
  const float* pred   = (const float*)d_in[1];
  const float* enc_w  = (const float*)d_in[2];
  const float* enc_b  = (const float*)d_in[3];
  const float* pred_w = (const float*)d_in[4];
  const float* pred_b = (const float*)d_in[5];
  const float* out_w  = (const float*)d_in[6];
  const float* out_b  = (const float*)d_in[7];
  float* out = (float*)d_out;

  char* ws = (char*)d_ws;
  __bf16* E  = (__bf16*)(ws);                 // 1024*640 bf16
  __bf16* P  = (__bf16*)(ws + 1310720);       //  256*640 bf16
  __bf16* Wb = (__bf16*)(ws + 1638400);       // pre-swizzled out_w half-tiles
  __bf16* Z  = (__bf16*)(ws + 2949120);       // 256*10*2*8192 bf16, pre-swizzled

  const int zpath = (ws_size >= (size_t)86835200) ? 1 : 0;

  prep_kernel<<<dim3(370), dim3(256), 0, stream>>>(
      enc, enc_w, enc_b, pred, pred_w, pred_b, out_w, E, P, Wb, zpath);

  if (zpath) {
    zprod_kernel<<<dim3(2560), dim3(256), 0, stream>>>(E, P, Z);
    joiner_8pr<<<dim3(1024), dim3(512), 0, stream>>>(Z, Wb, out_b, out);
  } else {
    joiner_fused<<<dim3(2048), dim3(512), 0, stream>>>(E, P, Wb, out_b, out);
  }
}

// Round 15
// 155.402 us; speedup vs baseline: 1.6140x; 1.0026x over previous
//
#include <hip/hip_runtime.h>
#include <cstdint>
#include <cstddef>

// RNNT joiner: logits[b,t,u,v] = sum_j tanh(E[b,t,j]+P[b,u,j]) * out_w[v,j] + out_b[v]
// B=4 T=256 U=64 D=512 J=640 V=1024.  M = 65536 rows (b,t,u), N=1024, K=640.
//
// ws layout (Z-path, R8 layouts — pass-proven):
//   E  : bf16 [1024][640]                  @ 0          (1,310,720 B)
//   P  : bf16 [ 256][640]                  @ 1,310,720  (  327,680 B)
//   Wb : bf16 [nt=4][kt=10][half=2][8192]  @ 1,638,400  (1,310,720 B)  pre-swz 128x64 half-tiles
//   Z  : bf16 [mt=256][kt=10][half=2][8192]@ 2,949,120  (83,886,080 B) pre-swz 128x64 half-tiles
// total 86,835,200 B.  ws_size smaller -> fused fallback.

typedef __attribute__((ext_vector_type(8))) __bf16 bf16x8;
typedef __attribute__((ext_vector_type(4))) float f32x4;

// XOR swizzle within a [128][64] bf16 half-tile (row stride 128B).
__device__ __forceinline__ int swz64(int row, int kElem) {
  return (row << 6) + (kElem ^ ((row & 7) << 3));
}

__device__ __forceinline__ float fast_tanh(float x) {
  float e = __builtin_amdgcn_exp2f(x * 2.88539008177793f);  // e^(2x)
  return 1.0f - 2.0f * __builtin_amdgcn_rcpf(e + 1.0f);
}

__device__ __forceinline__ void gload_lds16(const void* g, void* l) {
  __builtin_amdgcn_global_load_lds(
      (const __attribute__((address_space(1))) void*)g,
      (__attribute__((address_space(3))) void*)l, 16, 0, 0);
}

// Barrier that is also a compiler-level memory fence (zero extra HW instrs).
__device__ __forceinline__ void wg_barrier() {
  asm volatile("" ::: "memory");
  __builtin_amdgcn_s_barrier();
  asm volatile("" ::: "memory");
}

// ---------------------------------------------------------------------------
// proj tile: C[mt*128..][nt*128..] = A[128][512] . W[128][512]^T + bias  (bf16 out)
// ---------------------------------------------------------------------------
__device__ void proj_tile(const float* __restrict__ A, const float* __restrict__ W,
                          const float* __restrict__ bias, __bf16* __restrict__ C,
                          int mt, int nt, __bf16* As, __bf16* Bs)
{
  const int tid  = threadIdx.x;
  const int r = tid & 127, half = tid >> 7;
  const int lane = tid & 63, wv = tid >> 6;
  const int wm = wv >> 1, wn = wv & 1;

  const float* arow = A + (size_t)(mt * 128 + r) * 512 + half * 32;
  const float* wrow = W + (size_t)(nt * 128 + r) * 512 + half * 32;

  f32x4 acc[4][4] = {};

  for (int k0 = 0; k0 < 512; k0 += 64) {
#pragma unroll
    for (int s = 0; s < 4; ++s) {
      f32x4 a0 = *(const f32x4*)(arow + k0 + s * 8);
      f32x4 a1 = *(const f32x4*)(arow + k0 + s * 8 + 4);
      f32x4 w0 = *(const f32x4*)(wrow + k0 + s * 8);
      f32x4 w1 = *(const f32x4*)(wrow + k0 + s * 8 + 4);
      bf16x8 za, zw;
#pragma unroll
      for (int j = 0; j < 4; ++j) {
        za[j] = (__bf16)a0[j]; za[4 + j] = (__bf16)a1[j];
        zw[j] = (__bf16)w0[j]; zw[4 + j] = (__bf16)w1[j];
      }
      const int kk = half * 32 + s * 8;
      *(bf16x8*)&As[swz64(r, kk)] = za;
      *(bf16x8*)&Bs[swz64(r, kk)] = zw;
    }
    __syncthreads();
#pragma unroll
    for (int kk = 0; kk < 2; ++kk) {
      bf16x8 af[4], bfr[4];
#pragma unroll
      for (int i = 0; i < 4; ++i) {
        af[i]  = *(const bf16x8*)&As[swz64(wm * 64 + i * 16 + (lane & 15), kk * 32 + (lane >> 4) * 8)];
        bfr[i] = *(const bf16x8*)&Bs[swz64(wn * 64 + i * 16 + (lane & 15), kk * 32 + (lane >> 4) * 8)];
      }
#pragma unroll
      for (int mi = 0; mi < 4; ++mi)
#pragma unroll
        for (int ni = 0; ni < 4; ++ni)
          acc[mi][ni] = __builtin_amdgcn_mfma_f32_16x16x32_bf16(af[mi], bfr[ni], acc[mi][ni], 0, 0, 0);
    }
    __syncthreads();
  }

  const int rowbase = mt * 128 + wm * 64;
  const int colbase = nt * 128 + wn * 64;
#pragma unroll
  for (int ni = 0; ni < 4; ++ni) {
    const int col = colbase + ni * 16 + (lane & 15);
    const float bb = bias[col];
#pragma unroll
    for (int mi = 0; mi < 4; ++mi) {
      const int row = rowbase + mi * 16 + (lane >> 4) * 4;
#pragma unroll
      for (int rg = 0; rg < 4; ++rg)
        C[(size_t)(row + rg) * 640 + col] = (__bf16)(acc[mi][ni][rg] + bb);
    }
  }
}

// ---------------------------------------------------------------------------
// prep: blocks 0..39 enc-proj, 40..49 pred-proj, 50..369 out_w conversion.
// zpath=1: Wb [nt(4)][kt(10)][half(2)][128x64 swz64].
// zpath=0: Wb [nb(8)][kt(10)][128x64 swz64]  (fallback layout).
// ---------------------------------------------------------------------------
__global__ __launch_bounds__(256) void prep_kernel(
    const float* __restrict__ enc,  const float* __restrict__ enc_w,  const float* __restrict__ enc_b,
    const float* __restrict__ pred, const float* __restrict__ pred_w, const float* __restrict__ pred_b,
    const float* __restrict__ out_w,
    __bf16* __restrict__ E, __bf16* __restrict__ P, __bf16* __restrict__ Wb, int zpath)
{
  __shared__ __align__(16) __bf16 As[128 * 64];
  __shared__ __align__(16) __bf16 Bs[128 * 64];
  const int bid = blockIdx.x;
  if (bid < 40) {
    proj_tile(enc, enc_w, enc_b, E, bid / 5, bid % 5, As, Bs);
  } else if (bid < 50) {
    proj_tile(pred, pred_w, pred_b, P, (bid - 40) / 5, (bid - 40) % 5, As, Bs);
  } else {
    const int gid = (bid - 50) * 256 + threadIdx.x;  // 81920 total (1024*80)
    const int v  = gid / 80;
    const int j8 = gid % 80;
    f32x4 w0 = *(const f32x4*)(out_w + (size_t)v * 640 + j8 * 8);
    f32x4 w1 = *(const f32x4*)(out_w + (size_t)v * 640 + j8 * 8 + 4);
    bf16x8 z;
#pragma unroll
    for (int j = 0; j < 4; ++j) { z[j] = (__bf16)w0[j]; z[4 + j] = (__bf16)w1[j]; }
    if (zpath) {
      const int nt = v >> 8, vv = v & 255;
      const int half = vv >> 7, rr = vv & 127;
      const int kt = j8 >> 3, kk = (j8 & 7) * 8;
      *(bf16x8*)(Wb + (((size_t)(nt * 10 + kt) * 2 + half) << 13) + swz64(rr, kk)) = z;
    } else {
      const int nb = v >> 7, rr = v & 127;
      const int kb = j8 >> 3, kk = (j8 & 7) * 8;
      *(bf16x8*)(Wb + ((size_t)(nb * 10 + kb) << 13) + swz64(rr, kk)) = z;
    }
  }
}

// ---------------------------------------------------------------------------
// zprod: Z[mt][kt][half][8192] = tanh(E+P), pre-swizzled half-tiles, LINEAR
// stores (swizzle inverted at source index).  grid = 2560 (mt*10+kt), 256 thr.
// ---------------------------------------------------------------------------
__global__ __launch_bounds__(256) void zprod_kernel(
    const __bf16* __restrict__ E, const __bf16* __restrict__ P,
    __bf16* __restrict__ Z)
{
  const int bid = blockIdx.x;
  const int mt = bid / 10, kt = bid % 10;
  __bf16* zdst = Z + ((size_t)bid << 14);      // 16384 elems per (mt,kt)

#pragma unroll
  for (int c = 0; c < 8; ++c) {
    const int o = c * 2048 + threadIdx.x * 8;  // linear offset in 16K-elem block
    const int half = o >> 13, oo = o & 8191;
    const int rr = oo >> 6;
    const int r = half * 128 + rr;             // tile row 0..255
    const int k = kt * 64 + ((oo & 63) ^ ((rr & 7) << 3));
    const int grow = mt * 256 + r;             // global M-row
    const __bf16* ep = E + (size_t)(grow >> 6) * 640 + k;
    const __bf16* pp = P + (size_t)(((grow >> 14) << 6) | (grow & 63)) * 640 + k;
    bf16x8 e8 = *(const bf16x8*)ep;
    bf16x8 p8 = *(const bf16x8*)pp;
    bf16x8 z;
#pragma unroll
    for (int j = 0; j < 8; ++j)
      z[j] = (__bf16)fast_tanh((float)e8[j] + (float)p8[j]);
    *(bf16x8*)&zdst[o] = z;
  }
}

// ---------------------------------------------------------------------------
// main (Z-path): ONE-BARRIER-PER-TILE 256x256 GEMM (barrier-light rework of R8).
// 10 K-tiles (BK=64), 512 thr = 8 waves (2M x 4N), wave-tile 128x64,
// interleaved frags.  Per tile t (d=t&1):
//   1. issue all 8 global_load_lds for tile t+1 into buffers d^1
//      (t-1's buffers; their readers finished before the PREVIOUS barrier).
//   2. ds_read tile t with counted lgkm: afl(8)+bl(4) -> lgkm(4) -> 16 MFMA;
//      lgkm(0) [bh] -> 16 MFMA; read afh(8) AFTER afl dies (frag live <= 96
//      VGPR); lgkm(0) -> 32 MFMA.  LDS reads retire under MFMA.
//   3. vmcnt(0): t+1's loads were issued a FULL TILE BODY ago (~2000+ cyc)
//      -> drain is covered even for HBM misses.
//   4. wg_barrier: publishes t+1, and is the tail protecting the next WAR.
// 11 barriers total (vs ~75 in the 4-phase version).  LDS 128 KB, grid 1024
// XCD-chunked (4 nt-blocks of each mt share an XCD L2 for the Z strip).
// ---------------------------------------------------------------------------
__global__ __launch_bounds__(512, 2) void joiner_1b(
    const __bf16* __restrict__ Z, const __bf16* __restrict__ Wb,
    const float* __restrict__ outb, float* __restrict__ out)
{
  __shared__ __align__(16) __bf16 As[2][2][8192];   // [dbuf][half][128x64]
  __shared__ __align__(16) __bf16 Bs[2][2][8192];
  const int wg = blockIdx.x;
  const int bid = (wg & 7) * 128 + (wg >> 3);       // XCD-contiguous chunks
  const int mt = bid >> 2, nt = bid & 3;
  const int tid = threadIdx.x;
  const int lane = tid & 63, wv = tid >> 6;
  const int wm = wv >> 2, wn = wv & 3;              // 2 x 4 wave grid

  const int rb  = wm * 16 + (lane & 15);
  const int cb  = wn * 16 + (lane & 15);
  const int kb8 = (lane >> 4) * 8;

  const __bf16* zsrc = Z  + ((size_t)(mt * 20) << 13);  // [10][2][8192]
  const __bf16* wsrc = Wb + ((size_t)(nt * 20) << 13);

  f32x4 acc[8][4] = {};

  auto stA = [&](int kt, int half) {
    __bf16* dst = &As[kt & 1][half][wv * 512];
    const __bf16* src = zsrc + (((size_t)kt * 2 + half) << 13) + wv * 512 + lane * 8;
    gload_lds16(src, dst);
    gload_lds16(src + 4096, dst + 4096);
  };
  auto stB = [&](int kt, int half) {
    __bf16* dst = &Bs[kt & 1][half][wv * 512];
    const __bf16* src = wsrc + (((size_t)kt * 2 + half) << 13) + wv * 512 + lane * 8;
    gload_lds16(src, dst);
    gload_lds16(src + 4096, dst + 4096);
  };

  // ---- prologue: stage tile 0, drain, publish ----
  stA(0, 0); stA(0, 1); stB(0, 0); stB(0, 1);
  asm volatile("s_waitcnt vmcnt(0)" ::: "memory");
  wg_barrier();

#pragma unroll
  for (int t = 0; t < 10; ++t) {
    const int d = t & 1;
    const __bf16* A0 = &As[d][0][0];
    const __bf16* A1 = &As[d][1][0];
    const __bf16* B0 = &Bs[d][0][0];
    const __bf16* B1 = &Bs[d][1][0];

    // 1. issue next tile's staging (writes t-1's buffers; WAR-safe: their
    //    readers completed before the previous wg_barrier)
    if (t < 9) { stA(t + 1, 0); stA(t + 1, 1); stB(t + 1, 0); stB(t + 1, 1); }

    // 2. reads + MFMA with counted lgkm (DS completes in order)
    bf16x8 afl[4][2], bl[2][2], bh[2][2];
#pragma unroll
    for (int f = 0; f < 4; ++f)
#pragma unroll
      for (int kk = 0; kk < 2; ++kk)
        afl[f][kk] = *(const bf16x8*)&A0[swz64(f * 32 + rb, kk * 32 + kb8)];
#pragma unroll
    for (int g = 0; g < 2; ++g)
#pragma unroll
      for (int kk = 0; kk < 2; ++kk)
        bl[g][kk] = *(const bf16x8*)&B0[swz64(g * 64 + cb, kk * 32 + kb8)];
    __builtin_amdgcn_sched_barrier(0);     // pin: {afl,bl} issue before bh
#pragma unroll
    for (int g = 0; g < 2; ++g)
#pragma unroll
      for (int kk = 0; kk < 2; ++kk)
        bh[g][kk] = *(const bf16x8*)&B1[swz64(g * 64 + cb, kk * 32 + kb8)];
    asm volatile("s_waitcnt lgkmcnt(4)" ::: "memory");   // afl+bl done; bh in flight
    __builtin_amdgcn_sched_barrier(0);
    __builtin_amdgcn_s_setprio(1);
#pragma unroll
    for (int kk = 0; kk < 2; ++kk)
#pragma unroll
      for (int f = 0; f < 4; ++f)
#pragma unroll
        for (int g = 0; g < 2; ++g)
          acc[f][g] = __builtin_amdgcn_mfma_f32_16x16x32_bf16(afl[f][kk], bl[g][kk], acc[f][g], 0, 0, 0);
    __builtin_amdgcn_s_setprio(0);
    asm volatile("s_waitcnt lgkmcnt(0)" ::: "memory");   // bh done
    __builtin_amdgcn_sched_barrier(0);
    __builtin_amdgcn_s_setprio(1);
#pragma unroll
    for (int kk = 0; kk < 2; ++kk)
#pragma unroll
      for (int f = 0; f < 4; ++f)
#pragma unroll
        for (int g = 0; g < 2; ++g)
          acc[f][2 + g] = __builtin_amdgcn_mfma_f32_16x16x32_bf16(afl[f][kk], bh[g][kk], acc[f][2 + g], 0, 0, 0);
    __builtin_amdgcn_s_setprio(0);
    // afl dead -> read afh into recycled registers
    bf16x8 afh[4][2];
#pragma unroll
    for (int f = 0; f < 4; ++f)
#pragma unroll
      for (int kk = 0; kk < 2; ++kk)
        afh[f][kk] = *(const bf16x8*)&A1[swz64(f * 32 + rb, kk * 32 + kb8)];
    asm volatile("s_waitcnt lgkmcnt(0)" ::: "memory");   // afh done
    __builtin_amdgcn_sched_barrier(0);
    __builtin_amdgcn_s_setprio(1);
#pragma unroll
    for (int kk = 0; kk < 2; ++kk)
#pragma unroll
      for (int f = 0; f < 4; ++f)
#pragma unroll
        for (int g = 0; g < 2; ++g)
          acc[4 + f][2 + g] = __builtin_amdgcn_mfma_f32_16x16x32_bf16(afh[f][kk], bh[g][kk], acc[4 + f][2 + g], 0, 0, 0);
#pragma unroll
    for (int kk = 0; kk < 2; ++kk)
#pragma unroll
      for (int f = 0; f < 4; ++f)
#pragma unroll
        for (int g = 0; g < 2; ++g)
          acc[4 + f][g] = __builtin_amdgcn_mfma_f32_16x16x32_bf16(afh[f][kk], bl[g][kk], acc[4 + f][g], 0, 0, 0);
    __builtin_amdgcn_s_setprio(0);

    // 3+4. drain next tile's loads (issued a full tile ago) and publish
    if (t < 9) {
      asm volatile("s_waitcnt vmcnt(0)" ::: "memory");
      wg_barrier();
    }
  }

  // ---- epilogue: bias + store ----
  const int rowbase = (mt << 8) + wm * 16 + (lane >> 4) * 4;
  const int colbase = (nt << 8) + wn * 16 + (lane & 15);
#pragma unroll
  for (int g = 0; g < 4; ++g) {
    const int col = colbase + g * 64;
    const float bb = outb[col];
#pragma unroll
    for (int f = 0; f < 8; ++f) {
      const int row = rowbase + f * 32;
#pragma unroll
      for (int rg = 0; rg < 4; ++rg)
        out[(size_t)(row + rg) * 1024 + col] = acc[f][g][rg] + bb;
    }
  }
}

// ---------------------------------------------------------------------------
// Fallback (small ws): R5 fused kernel, Wb in [8][10][128x64 swz64] layout.
// ---------------------------------------------------------------------------
__global__ __launch_bounds__(512, 4) void joiner_fused(
    const __bf16* __restrict__ E, const __bf16* __restrict__ P,
    const __bf16* __restrict__ Wb, const float* __restrict__ outb,
    float* __restrict__ out)
{
  __shared__ __align__(16) __bf16 As[8192];
  __shared__ __align__(16) __bf16 Bs[2][16384];
  const int tid = threadIdx.x;
  const int nt = blockIdx.x & 3;
  const int mt = blockIdx.x >> 2;
  const int row0 = mt << 7;
  const int b  = row0 >> 14;
  const int t0 = (row0 >> 6) & 255;
  const int ar = tid & 127, h = tid >> 7;
  const int lane = tid & 63, wv = tid >> 6;
  const int wm = wv >> 2, wn = wv & 3;

  const __bf16* ep = E + (size_t)((b << 8) + t0 + (ar >> 6)) * 640 + h * 16;
  const __bf16* pp = P + (size_t)((b << 6) + (ar & 63)) * 640 + h * 16;

  f32x4 acc[4][4] = {};
  bf16x8 eA[2], pA[2];

  auto stageB2 = [&](int kt, __bf16* dst) {
#pragma unroll
    for (int c = 0; c < 4; ++c) {
      const int blk = nt * 2 + (c >> 1);
      const int inoff = (c & 1) * 4096 + wv * 512;
      gload_lds16(Wb + ((size_t)(blk * 10 + kt) << 13) + inoff + lane * 8,
                  dst + (c >> 1) * 8192 + inoff);
    }
  };
  auto loadEP = [&](int k0) {
#pragma unroll
    for (int c = 0; c < 2; ++c) {
      eA[c] = *(const bf16x8*)(ep + k0 + c * 8);
      pA[c] = *(const bf16x8*)(pp + k0 + c * 8);
    }
  };
  auto writeA = [&]() {
#pragma unroll
    for (int c = 0; c < 2; ++c) {
      bf16x8 z;
#pragma unroll
      for (int j = 0; j < 8; ++j)
        z[j] = (__bf16)fast_tanh((float)eA[c][j] + (float)pA[c][j]);
      *(bf16x8*)&As[swz64(ar, h * 16 + c * 8)] = z;
    }
  };
  auto compute = [&](const __bf16* Bsc) {
#pragma unroll
    for (int kk = 0; kk < 2; ++kk) {
      bf16x8 af[4], bfr[4];
#pragma unroll
      for (int i = 0; i < 4; ++i) {
        af[i]  = *(const bf16x8*)&As[swz64(wm * 64 + i * 16 + (lane & 15), kk * 32 + (lane >> 4) * 8)];
        bfr[i] = *(const bf16x8*)&Bsc[swz64(wn * 64 + i * 16 + (lane & 15), kk * 32 + (lane >> 4) * 8)];
      }
      asm volatile("s_waitcnt lgkmcnt(0)" ::: "memory");
      __builtin_amdgcn_sched_barrier(0);
      __builtin_amdgcn_s_setprio(1);
#pragma unroll
      for (int mi = 0; mi < 4; ++mi)
#pragma unroll
        for (int ni = 0; ni < 4; ++ni)
          acc[mi][ni] = __builtin_amdgcn_mfma_f32_16x16x32_bf16(af[mi], bfr[ni], acc[mi][ni], 0, 0, 0);
      __builtin_amdgcn_s_setprio(0);
    }
  };

  stageB2(0, Bs[0]);
  loadEP(0);
  writeA();
  asm volatile("s_waitcnt vmcnt(0) lgkmcnt(0)" ::: "memory");
  wg_barrier();

  for (int kt = 0; kt < 9; ++kt) {
    const int cur = kt & 1;
    stageB2(kt + 1, Bs[cur ^ 1]);
    loadEP((kt + 1) << 6);
    compute(Bs[cur]);
    wg_barrier();
    __builtin_amdgcn_sched_barrier(0);
    writeA();
    asm volatile("s_waitcnt lgkmcnt(0)" ::: "memory");
    wg_barrier();
  }
  compute(Bs[1]);

  const int rowbase = row0 + wm * 64;
  const int colbase = (nt << 8) + wn * 64;
#pragma unroll
  for (int ni = 0; ni < 4; ++ni) {
    const int col = colbase + ni * 16 + (lane & 15);
    const float bb = outb[col];
#pragma unroll
    for (int mi = 0; mi < 4; ++mi) {
      const int row = rowbase + mi * 16 + (lane >> 4) * 4;
#pragma unroll
      for (int rg = 0; rg < 4; ++rg)
        out[(size_t)(row + rg) * 1024 + col] = acc[mi][ni][rg] + bb;
    }
  }
}

extern "C" void kernel_launch(void* const* d_in, const int* in_sizes, int n_in,
                              void* d_out, int out_size, void* d_ws, size_t ws_size,
                              hipStream_t stream) {
  const float* enc    = (const float*)d_in[0];
  const float* pred   = (const float*)d_in[1];
  const float* enc_w  = (const float*)d_in[2];
  const float* enc_b  = (const float*)d_in[3];
  const float* pred_w = (const float*)d_in[4];
  const float* pred_b = (const float*)d_in[5];
  const float* out_w  = (const float*)d_in[6];
  const float* out_b  = (const float*)d_in[7];
  float* out = (float*)d_out;

  char* ws = (char*)d_ws;
  __bf16* E  = (__bf16*)(ws);                 // 1024*640 bf16
  __bf16* P  = (__bf16*)(ws + 1310720);       //  256*640 bf16
  __bf16* Wb = (__bf16*)(ws + 1638400);       // pre-swizzled out_w half-tiles
  __bf16* Z  = (__bf16*)(ws + 2949120);       // 256*10*2*8192 bf16, pre-swizzled

  const int zpath = (ws_size >= (size_t)86835200) ? 1 : 0;

  prep_kernel<<<dim3(370), dim3(256), 0, stream>>>(
      enc, enc_w, enc_b, pred, pred_w, pred_b, out_w, E, P, Wb, zpath);

  if (zpath) {
    zprod_kernel<<<dim3(2560), dim3(256), 0, stream>>>(E, P, Z);
    joiner_1b<<<dim3(1024), dim3(512), 0, stream>>>(Z, Wb, out_b, out);
  } else {
    joiner_fused<<<dim3(2048), dim3(512), 0, stream>>>(E, P, Wb, out_b, out);
  }
}